// Round 6
// baseline (2549.698 us; speedup 1.0000x reference)
//
#include <hip/hip_runtime.h>
#include <stdint.h>

// BiLSTM: B=32, T=256, D=1024, H=1024. out (B,T,2H) fp32.
//  k_cvt_x   : x fp32 -> bf16
//  k_pack_wxt: x-part of W{f,i,c,o} -> Wx^T bf16 [4096 gc][1024 k]
//  k_pgemm   : P[t][b][gc] = x@Wx + b (bf16 MFMA 32x32x16), shared by both dirs
//  k_lstm    : persistent 256-WG kernel; weights in LDS; h exchanged per step.
// R6: hierarchical signaling to kill LLC poll congestion (R5 est. ~6-12 TB/s
//     of coherent poll reads). Producers -> per-WG flag lines (unchanged);
//     wave 2 of WG0/WG1 aggregates its half's 128 flags into ONE step-flag;
//     consumers poll only the step-flag (1 transaction/wave/iter + sleep).
//     Everything else identical to R5.

typedef __attribute__((ext_vector_type(8))) short bf16x8;
typedef __attribute__((ext_vector_type(4))) float f32x4;
typedef __attribute__((ext_vector_type(16))) float f32x16;

// ---- workspace layout (bytes) ----
static const size_t XB_OFF  = 0;                 // x bf16: 16 MB
static const size_t WXT_OFF = 16777216;          // Wx^T bf16: 8 MB
static const size_t P2_OFF  = 25165824;          // P bf16: [256][32][4096] = 64 MB
static const size_t HB_OFF  = 92274688;          // h ring bf16: [2 dir][2 slot][32][1024]
static const size_t FLG_OFF = 92536832;          // flags u32 @64B stride: [2 half][128]
                                                 //  + step-flags u32 @64B: [2 half]
static const size_t FLG_SZ  = 16512;

__device__ __forceinline__ unsigned short f2bf(float f) {
    union { float f; unsigned u; } v; v.f = f;
    unsigned r = v.u + 0x7FFFu + ((v.u >> 16) & 1u);
    return (unsigned short)(r >> 16);
}
__device__ __forceinline__ float bf2f(unsigned short h) {
    union { unsigned u; float f; } v; v.u = ((unsigned)h) << 16; return v.f;
}
__device__ __forceinline__ float sigm(float x) {
    return 1.0f / (1.0f + exp2f(x * -1.4426950408889634f));
}
__device__ __forceinline__ float tanh_(float x) {
    return 1.0f - 2.0f / (1.0f + exp2f(x * 2.8853900817779268f));
}
__device__ __forceinline__ void gload16(const void* g, void* l) {
    __builtin_amdgcn_global_load_lds(
        (const __attribute__((address_space(1))) unsigned int*)g,
        (__attribute__((address_space(3))) unsigned int*)l, 16, 0, 0);
}
// SC1 (agent-coherent, LLC) variant: CPol bit 16. Validated R4/R5.
__device__ __forceinline__ void gload16a(const void* g, void* l) {
    __builtin_amdgcn_global_load_lds(
        (const __attribute__((address_space(1))) unsigned int*)g,
        (__attribute__((address_space(3))) unsigned int*)l, 16, 0, 16);
}

// ---------------- x -> bf16 ----------------
__global__ void k_cvt_x(const float* __restrict__ x, unsigned short* __restrict__ xb, int n) {
    int i = (blockIdx.x * blockDim.x + threadIdx.x) * 4;
    if (i < n) {
        float4 v = *(const float4*)(x + i);
        ushort4 o; o.x = f2bf(v.x); o.y = f2bf(v.y); o.z = f2bf(v.z); o.w = f2bf(v.w);
        *(ushort4*)(xb + i) = o;
    }
}

// ---------------- Wx^T pack ----------------
__global__ __launch_bounds__(256) void k_pack_wxt(
        const float* __restrict__ Wf, const float* __restrict__ Wi,
        const float* __restrict__ Wc, const float* __restrict__ Wo,
        unsigned short* __restrict__ wxt) {
    __shared__ unsigned short tile[64][66];
    const int k0 = blockIdx.x * 64;
    const int gate = blockIdx.y >> 4;
    const int c0 = (blockIdx.y & 15) * 64;
    const float* W = gate == 0 ? Wf : gate == 1 ? Wi : gate == 2 ? Wc : Wo;
    const int t = threadIdx.x;
    #pragma unroll
    for (int i = 0; i < 4; ++i) {
        int id = t + 256 * i;
        int r = id >> 4, fq = id & 15;
        const float* src = W + (size_t)(1024 + k0 + r) * 1024 + c0 + fq * 4;
        float4 v = *(const float4*)src;
        tile[r][fq*4+0] = f2bf(v.x); tile[r][fq*4+1] = f2bf(v.y);
        tile[r][fq*4+2] = f2bf(v.z); tile[r][fq*4+3] = f2bf(v.w);
    }
    __syncthreads();
    #pragma unroll
    for (int i = 0; i < 2; ++i) {
        int id = t + 256 * i;
        int c = id >> 3, kq = id & 7;
        ushort4 a, b;
        a.x = tile[kq*8+0][c]; a.y = tile[kq*8+1][c]; a.z = tile[kq*8+2][c]; a.w = tile[kq*8+3][c];
        b.x = tile[kq*8+4][c]; b.y = tile[kq*8+5][c]; b.z = tile[kq*8+6][c]; b.w = tile[kq*8+7][c];
        unsigned short* o = wxt + (size_t)(gate*1024 + c0 + c) * 1024 + k0 + kq*8;
        *(ushort4*)o = a;
        *((ushort4*)o + 1) = b;
    }
}

// ---------------- P GEMM ----------------
__global__ __launch_bounds__(256) void k_pgemm(
        const unsigned short* __restrict__ xb, const unsigned short* __restrict__ wxt,
        const float* __restrict__ b0, const float* __restrict__ b1,
        const float* __restrict__ b2, const float* __restrict__ b3,
        unsigned short* __restrict__ p2) {
    __shared__ char lds[32768];
    const int n0 = blockIdx.x * 128;
    const int gc0 = blockIdx.y * 128;
    const int tid = threadIdx.x;
    const int lane = tid & 63, w = tid >> 6;
    f32x16 acc[4];
    #pragma unroll
    for (int i = 0; i < 4; ++i)
        #pragma unroll
        for (int j = 0; j < 16; ++j) acc[i][j] = 0.0f;

    for (int kt = 0; kt < 16; ++kt) {
        const int k0 = kt * 64;
        #pragma unroll
        for (int i = 0; i < 4; ++i) {
            int widx = w*4 + i;
            int n = widx*64 + lane;
            int mt = n >> 8, kc = (n >> 5) & 7, r5 = n & 31;
            gload16(xb  + (size_t)(n0  + mt*32 + r5)*1024 + k0 + kc*8, lds + widx*1024);
            gload16(wxt + (size_t)(gc0 + mt*32 + r5)*1024 + k0 + kc*8, lds + 16384 + widx*1024);
        }
        __syncthreads();
        bf16x8 a[4];
        #pragma unroll
        for (int ks = 0; ks < 4; ++ks)
            a[ks] = *(const bf16x8*)(lds + w*4096 + (ks*2 + (lane>>5))*512 + (lane&31)*16);
        #pragma unroll
        for (int nt = 0; nt < 4; ++nt) {
            #pragma unroll
            for (int ks = 0; ks < 4; ++ks) {
                bf16x8 b = *(const bf16x8*)(lds + 16384 + nt*4096 + (ks*2 + (lane>>5))*512 + (lane&31)*16);
                acc[nt] = __builtin_amdgcn_mfma_f32_32x32x16_bf16(a[ks], b, acc[nt], 0, 0, 0);
            }
        }
        __syncthreads();
    }
    const int b_idx = n0 >> 8;
    const int t_base = n0 & 255;
    #pragma unroll
    for (int nt = 0; nt < 4; ++nt) {
        int gc = gc0 + nt*32 + (lane & 31);
        int gate = gc >> 10, col = gc & 1023;
        const float* bp = gate == 0 ? b0 : gate == 1 ? b1 : gate == 2 ? b2 : b3;
        float bias = bp[col];
        #pragma unroll
        for (int r = 0; r < 16; ++r) {
            int row = (r & 3) + 8*(r >> 2) + 4*(lane >> 5);
            int t = t_base + w*32 + row;
            p2[((size_t)t*32 + b_idx)*4096 + gc] = f2bf(acc[nt][r] + bias);
        }
    }
}

// ---------------- persistent BiLSTM recurrence ----------------
#define WPK   0          // 64 KB weight pack (B-frag order, 16x16x32)
#define HFO   65536      // 32 KB h stage, dir F (A-frag order, xor-swizzled)
#define HBO   98304      // 32 KB h stage, dir B
#define REDF  131072     // 4 KB K-split partials F
#define REDB  135168     // 4 KB partials B
#define CSTO  139264     // 1 KB c-state
#define STH_H 140288     // 512 B h bf16 stash [2 dir][16 row][8 col]
#define STH_O 140800     // 1 KB out fp32 stash [2 dir][16 row][8 col]
#define LDS_TOT 141824

extern __shared__ char smem[];

__global__ __launch_bounds__(256, 1) void k_lstm(
    const float* __restrict__ Wf, const float* __restrict__ Wi,
    const float* __restrict__ Wc, const float* __restrict__ Wo,
    const unsigned short* __restrict__ p2,
    unsigned short* __restrict__ hbuf,   // [2 dir][2 slot][32][1024] bf16
    unsigned* __restrict__ fl,           // [half][128] u32 @64B + stepflags @+16384
    float* __restrict__ out)             // [32][256][2048] fp32
{
    const int wg = blockIdx.x;
    const int bh = wg & 1;               // batch half (own dependency group)
    const int hc0 = (wg >> 1) * 8;       // owned h-cols
    const int tid = threadIdx.x;
    const int lane = tid & 63, w = tid >> 6;
    unsigned* stepfl = fl + 4096;        // u32[2 half] @ 64B stride
    __shared__ int s_abort;
    if (tid == 0) s_abort = 0;

    // ---- pack recurrent weights (h-part rows 0..1023) into LDS frag order ----
    {
        unsigned short* scr = (unsigned short*)(smem + HFO);
        const float* Wp[4] = {Wf, Wi, Wc, Wo};
        for (int blk = 0; blk < 16; ++blk) {
            int r0 = blk * 64;
            {
                int g = tid >> 6, r = tid & 63;
                const float* src = Wp[g] + (size_t)(r0 + r) * 1024 + hc0;
                float4 v0 = *(const float4*)src;
                float4 v1 = *(const float4*)(src + 4);
                unsigned short* d = scr + r*32 + g*8;
                d[0]=f2bf(v0.x); d[1]=f2bf(v0.y); d[2]=f2bf(v0.z); d[3]=f2bf(v0.w);
                d[4]=f2bf(v1.x); d[5]=f2bf(v1.y); d[6]=f2bf(v1.z); d[7]=f2bf(v1.w);
            }
            __syncthreads();
            {
                int ksl = tid >> 7, nt = (tid >> 6) & 1, l = tid & 63;
                int gcl = nt*16 + (l & 15);
                int gp = gcl >> 3, hc = gcl & 7;
                int ks = (r0 >> 5) + ksl;
                unsigned short tmp[8];
                #pragma unroll
                for (int j = 0; j < 8; ++j) {
                    int kloc = ksl*32 + (l >> 4)*8 + j;
                    tmp[j] = scr[kloc*32 + gp*8 + hc];
                }
                char* dst = smem + WPK + (size_t)((nt*32 + ks)*64 + l)*16;
                ushort4 lo, hi;
                lo.x=tmp[0]; lo.y=tmp[1]; lo.z=tmp[2]; lo.w=tmp[3];
                hi.x=tmp[4]; hi.y=tmp[5]; hi.z=tmp[6]; hi.w=tmp[7];
                *(ushort4*)dst = lo; *((ushort4*)dst + 1) = hi;
            }
            __syncthreads();
        }
    }

    // ---- init c=0 (LDS), h[0]=0 (global), publish tag 1 ----
    for (int i = tid; i < 256; i += 256) ((float*)(smem + CSTO))[i] = 0.0f;
    const int d2 = tid >> 7, t2 = tid & 127;
    const int eb = t2 >> 3, ehc = t2 & 7;
    const int ebg = bh*16 + eb, ehcg = hc0 + ehc;
    if ((tid & 1) == 0) {
        unsigned* dst = (unsigned*)(hbuf + ((size_t)d2*2 + 0)*32768 + (size_t)ebg*1024 + ehcg);
        __hip_atomic_store(dst, 0u, __ATOMIC_RELAXED, __HIP_MEMORY_SCOPE_AGENT);
    }
    __syncthreads();                              // drains init stores (vmcnt0)
    if (tid == 0)
        __hip_atomic_store(fl + (size_t)bh*2048 + (wg >> 1)*16, 1u,
                           __ATOMIC_RELAXED, __HIP_MEMORY_SCOPE_AGENT);

    for (int s = 0; s < 256; ++s) {
        const int slot = s & 1, nslot = slot ^ 1;
        const int tx = d2 ? (255 - s) : s;
        const unsigned tag = (unsigned)(s + 1);
        // P prefetch (cached loads; no h dependency; hidden under spin+staging)
        const unsigned short* pp = p2 + ((size_t)tx*32 + ebg)*4096 + ehcg;
        unsigned short pf = pp[0], pi = pp[1024], pc = pp[2048], po = pp[3072];

        // ---- consumers: wave 0 polls the single step-flag for own half ----
        if (w == 0) {
            const unsigned* sf = stepfl + (size_t)bh*16;
            long guard = 0; unsigned v;
            for (;;) {
                v = __hip_atomic_load(sf, __ATOMIC_RELAXED, __HIP_MEMORY_SCOPE_AGENT);
                if (v >= tag) break;
                if (++guard >= (1L << 21)) { v = 0xFFFFFFFFu; break; }
                __builtin_amdgcn_s_sleep(1);
            }
            if (lane == 0 && v == 0xFFFFFFFFu) s_abort = 1;
        }
        // ---- aggregator: wave 2 of WG0 (half 0) / WG1 (half 1) ----
        if (wg == bh && w == 2) {
            const unsigned* p0 = fl + (size_t)bh*2048 + lane*16;
            const unsigned* p1 = p0 + 64*16;
            long guard = 0; int timeout = 0;
            for (;;) {
                unsigned a = __hip_atomic_load(p0, __ATOMIC_RELAXED, __HIP_MEMORY_SCOPE_AGENT);
                unsigned b = __hip_atomic_load(p1, __ATOMIC_RELAXED, __HIP_MEMORY_SCOPE_AGENT);
                if (__all((a >= tag) && (b >= tag))) break;
                if (++guard >= (1L << 21)) { timeout = 1; break; }
            }
            if (lane == 0)
                __hip_atomic_store(stepfl + (size_t)bh*16,
                                   timeout ? 0xFFFFFFFFu : tag,
                                   __ATOMIC_RELAXED, __HIP_MEMORY_SCOPE_AGENT);
        }
        __syncthreads();
        if (s_abort) break;

        // ---- stage h (both dirs) via global_load_lds SC1, pre-swizzled src ----
        {
            const unsigned short* hsF = hbuf + ((size_t)0*2 + slot)*32768;
            const unsigned short* hsB = hbuf + ((size_t)1*2 + slot)*32768;
            #pragma unroll
            for (int j = 0; j < 8; ++j) {
                int c = w*8 + j;                  // chunks 0..31
                int kc = c*4 + (lane >> 4);
                int r16 = (lane & 15) ^ (kc & 7);
                size_t off = (size_t)(bh*16 + r16)*1024 + kc*8;
                gload16a(hsF + off, smem + HFO + c*1024);
                gload16a(hsB + off, smem + HBO + c*1024);
            }
        }
        __syncthreads();                          // drains vmcnt (staging + P)

        // ---- MFMA: gates = h @ Wh (M=16, N=32, K=1024), K split across wave pairs ----
        {
            const int nt = w & 1, kh = w >> 1;
            f32x4 aF = {0.f,0.f,0.f,0.f}, aB = {0.f,0.f,0.f,0.f};
            #pragma unroll 4
            for (int k8 = 0; k8 < 16; ++k8) {
                int ks = kh*16 + k8;
                int kc = ks*4 + (lane >> 4);
                int ao = kc*256 + (((lane & 15)*16) ^ ((kc & 7) << 4));
                bf16x8 bfr = *(const bf16x8*)(smem + WPK + (size_t)((nt*32 + ks)*64 + lane)*16);
                bf16x8 afF = *(const bf16x8*)(smem + HFO + ao);
                aF = __builtin_amdgcn_mfma_f32_16x16x32_bf16(afF, bfr, aF, 0, 0, 0);
                bf16x8 afB = *(const bf16x8*)(smem + HBO + ao);
                aB = __builtin_amdgcn_mfma_f32_16x16x32_bf16(afB, bfr, aB, 0, 0, 0);
            }
            float* rf = (float*)(smem + REDF) + w*256;
            float* rb = (float*)(smem + REDB) + w*256;
            #pragma unroll
            for (int r = 0; r < 4; ++r) {
                int row = (lane >> 4)*4 + r;
                rf[row*16 + (lane & 15)] = aF[r];
                rb[row*16 + (lane & 15)] = aB[r];
            }
        }
        __syncthreads();

        // ---- elementwise: t<128 does F, t>=128 does B; stash h+out in LDS ----
        {
            const char* red = smem + (d2 ? REDB : REDF);
            float* cst = (float*)(smem + CSTO) + (size_t)(d2*16 + eb)*8 + ehc;
            unsigned short pv[4] = {pf, pi, pc, po};
            float pre[4];
            #pragma unroll
            for (int g = 0; g < 4; ++g) {
                int gc = g*8 + ehc;
                int nt = gc >> 4, col = gc & 15;
                float s0 = ((const float*)red)[nt*256 + eb*16 + col];
                float s1 = ((const float*)red)[(2 + nt)*256 + eb*16 + col];
                pre[g] = s0 + s1 + bf2f(pv[g]);
            }
            float fg = sigm(pre[0]), ig = sigm(pre[1]), gg = tanh_(pre[2]), og = sigm(pre[3]);
            float cn = fg * (*cst) + ig * gg;
            *cst = cn;
            float hv = og * tanh_(cn);
            ((unsigned short*)(smem + STH_H))[d2*128 + t2] = f2bf(hv);
            ((float*)(smem + STH_O))[d2*128 + t2] = hv;
        }
        __syncthreads();

        // ---- h publish: 64 threads x 8B agent stores (aligned pairs) ----
        if (tid < 64) {
            int chunk = tid >> 1, half = tid & 1;   // chunk = d2s*16 + ebs
            int d2s = chunk >> 4, ebs = chunk & 15;
            unsigned long long v = *(const unsigned long long*)(smem + STH_H + chunk*16 + half*8);
            unsigned long long* dst = (unsigned long long*)(hbuf
                + ((size_t)d2s*2 + nslot)*32768
                + (size_t)(bh*16 + ebs)*1024 + hc0 + half*4);
            __hip_atomic_store(dst, v, __ATOMIC_RELAXED, __HIP_MEMORY_SCOPE_AGENT);
        }
        __syncthreads();                          // drains h stores (vmcnt0)
        if (tid == 0)
            __hip_atomic_store(fl + (size_t)bh*2048 + (wg >> 1)*16, (unsigned)(s + 2),
                               __ATOMIC_RELAXED, __HIP_MEMORY_SCOPE_AGENT);

        // ---- out stores (post-publish, off critical path): 16B chunks ----
        if (tid >= 64 && tid < 128) {
            int i = tid - 64;
            int chunk = i >> 1, half = i & 1;       // chunk = d2s*16 + ebs
            int d2s = chunk >> 4, ebs = chunk & 15;
            int txs = d2s ? (255 - s) : s;
            float4 v = *(const float4*)(smem + STH_O + chunk*32 + half*16);
            *(float4*)(out + ((size_t)(bh*16 + ebs)*256 + txs)*2048
                           + (size_t)d2s*1024 + hc0 + half*4) = v;
        }
    }
}

extern "C" void kernel_launch(void* const* d_in, const int* in_sizes, int n_in,
                              void* d_out, int out_size, void* d_ws, size_t ws_size,
                              hipStream_t stream) {
    const float* x  = (const float*)d_in[0];
    const float* Wf = (const float*)d_in[1]; const float* bf_ = (const float*)d_in[2];
    const float* Wi = (const float*)d_in[3]; const float* bi_ = (const float*)d_in[4];
    const float* Wc = (const float*)d_in[5]; const float* bc_ = (const float*)d_in[6];
    const float* Wo = (const float*)d_in[7]; const float* bo_ = (const float*)d_in[8];
    char* ws = (char*)d_ws;
    unsigned short* xb   = (unsigned short*)(ws + XB_OFF);
    unsigned short* wxt  = (unsigned short*)(ws + WXT_OFF);
    unsigned short* p2   = (unsigned short*)(ws + P2_OFF);
    unsigned short* hbuf = (unsigned short*)(ws + HB_OFF);
    unsigned*       fl   = (unsigned*)(ws + FLG_OFF);

    hipMemsetAsync(ws + FLG_OFF, 0, FLG_SZ, stream);
    k_cvt_x<<<8192, 256, 0, stream>>>(x, xb, 32*256*1024);
    k_pack_wxt<<<dim3(16, 64), 256, 0, stream>>>(Wf, Wi, Wc, Wo, wxt);
    k_pgemm<<<dim3(64, 32), 256, 0, stream>>>(xb, wxt, bf_, bi_, bc_, bo_, p2);
    hipFuncSetAttribute((const void*)k_lstm, hipFuncAttributeMaxDynamicSharedMemorySize, LDS_TOT);
    k_lstm<<<256, 256, LDS_TOT, stream>>>(Wf, Wi, Wc, Wo, p2, hbuf, fl, (float*)d_out);
}

// Round 7
// 2532.154 us; speedup vs baseline: 1.0069x; 1.0069x over previous
//
#include <hip/hip_runtime.h>
#include <stdint.h>

// BiLSTM: B=32, T=256, D=1024, H=1024. out (B,T,2H) fp32.
//  k_cvt_x   : x fp32 -> bf16
//  k_pack_wxt: x-part of W{f,i,c,o} -> Wx^T bf16 [4096 gc][1024 k]
//  k_pgemm   : P[t][b][gc] = x@Wx + b (bf16 MFMA 32x32x16), shared by both dirs
//  k_lstm    : persistent 256-WG kernel; weights in LDS; h exchanged per step.
// R7: wave-specialized steady loop with RAW s_barrier + minimal manual waits
//     (kills the ~6x full vmcnt(0) drains/step that __syncthreads forced):
//     W0 poll+stage-F, W3 stage-B, W2 h-publish+flag, W1 out-stores (never
//     drained in-loop). P prefetched 1 step ahead into regs (static rotation).
//     R5 direct 128-flag poll restored (R6 aggregator hop cost +0.6us/step).

typedef __attribute__((ext_vector_type(8))) short bf16x8;
typedef __attribute__((ext_vector_type(4))) float f32x4;
typedef __attribute__((ext_vector_type(16))) float f32x16;

// ---- workspace layout (bytes) ----
static const size_t XB_OFF  = 0;                 // x bf16: 16 MB
static const size_t WXT_OFF = 16777216;          // Wx^T bf16: 8 MB
static const size_t P2_OFF  = 25165824;          // P bf16: [256][32][4096] = 64 MB
static const size_t HB_OFF  = 92274688;          // h ring bf16: [2 dir][2 slot][32][1024]
static const size_t FLG_OFF = 92536832;          // flags u32 @64B stride: [2 half][128]
static const size_t FLG_SZ  = 16384;

__device__ __forceinline__ unsigned short f2bf(float f) {
    union { float f; unsigned u; } v; v.f = f;
    unsigned r = v.u + 0x7FFFu + ((v.u >> 16) & 1u);
    return (unsigned short)(r >> 16);
}
__device__ __forceinline__ float bf2f(unsigned short h) {
    union { unsigned u; float f; } v; v.u = ((unsigned)h) << 16; return v.f;
}
__device__ __forceinline__ float sigm(float x) {
    return 1.0f / (1.0f + exp2f(x * -1.4426950408889634f));
}
__device__ __forceinline__ float tanh_(float x) {
    return 1.0f - 2.0f / (1.0f + exp2f(x * 2.8853900817779268f));
}
__device__ __forceinline__ void gload16(const void* g, void* l) {
    __builtin_amdgcn_global_load_lds(
        (const __attribute__((address_space(1))) unsigned int*)g,
        (__attribute__((address_space(3))) unsigned int*)l, 16, 0, 0);
}
// SC1 (agent-coherent, LLC) variant: CPol bit 16. Validated R4-R6.
__device__ __forceinline__ void gload16a(const void* g, void* l) {
    __builtin_amdgcn_global_load_lds(
        (const __attribute__((address_space(1))) unsigned int*)g,
        (__attribute__((address_space(3))) unsigned int*)l, 16, 0, 16);
}

// ---------------- x -> bf16 ----------------
__global__ void k_cvt_x(const float* __restrict__ x, unsigned short* __restrict__ xb, int n) {
    int i = (blockIdx.x * blockDim.x + threadIdx.x) * 4;
    if (i < n) {
        float4 v = *(const float4*)(x + i);
        ushort4 o; o.x = f2bf(v.x); o.y = f2bf(v.y); o.z = f2bf(v.z); o.w = f2bf(v.w);
        *(ushort4*)(xb + i) = o;
    }
}

// ---------------- Wx^T pack ----------------
__global__ __launch_bounds__(256) void k_pack_wxt(
        const float* __restrict__ Wf, const float* __restrict__ Wi,
        const float* __restrict__ Wc, const float* __restrict__ Wo,
        unsigned short* __restrict__ wxt) {
    __shared__ unsigned short tile[64][66];
    const int k0 = blockIdx.x * 64;
    const int gate = blockIdx.y >> 4;
    const int c0 = (blockIdx.y & 15) * 64;
    const float* W = gate == 0 ? Wf : gate == 1 ? Wi : gate == 2 ? Wc : Wo;
    const int t = threadIdx.x;
    #pragma unroll
    for (int i = 0; i < 4; ++i) {
        int id = t + 256 * i;
        int r = id >> 4, fq = id & 15;
        const float* src = W + (size_t)(1024 + k0 + r) * 1024 + c0 + fq * 4;
        float4 v = *(const float4*)src;
        tile[r][fq*4+0] = f2bf(v.x); tile[r][fq*4+1] = f2bf(v.y);
        tile[r][fq*4+2] = f2bf(v.z); tile[r][fq*4+3] = f2bf(v.w);
    }
    __syncthreads();
    #pragma unroll
    for (int i = 0; i < 2; ++i) {
        int id = t + 256 * i;
        int c = id >> 3, kq = id & 7;
        ushort4 a, b;
        a.x = tile[kq*8+0][c]; a.y = tile[kq*8+1][c]; a.z = tile[kq*8+2][c]; a.w = tile[kq*8+3][c];
        b.x = tile[kq*8+4][c]; b.y = tile[kq*8+5][c]; b.z = tile[kq*8+6][c]; b.w = tile[kq*8+7][c];
        unsigned short* o = wxt + (size_t)(gate*1024 + c0 + c) * 1024 + k0 + kq*8;
        *(ushort4*)o = a;
        *((ushort4*)o + 1) = b;
    }
}

// ---------------- P GEMM ----------------
__global__ __launch_bounds__(256) void k_pgemm(
        const unsigned short* __restrict__ xb, const unsigned short* __restrict__ wxt,
        const float* __restrict__ b0, const float* __restrict__ b1,
        const float* __restrict__ b2, const float* __restrict__ b3,
        unsigned short* __restrict__ p2) {
    __shared__ char lds[32768];
    const int n0 = blockIdx.x * 128;
    const int gc0 = blockIdx.y * 128;
    const int tid = threadIdx.x;
    const int lane = tid & 63, w = tid >> 6;
    f32x16 acc[4];
    #pragma unroll
    for (int i = 0; i < 4; ++i)
        #pragma unroll
        for (int j = 0; j < 16; ++j) acc[i][j] = 0.0f;

    for (int kt = 0; kt < 16; ++kt) {
        const int k0 = kt * 64;
        #pragma unroll
        for (int i = 0; i < 4; ++i) {
            int widx = w*4 + i;
            int n = widx*64 + lane;
            int mt = n >> 8, kc = (n >> 5) & 7, r5 = n & 31;
            gload16(xb  + (size_t)(n0  + mt*32 + r5)*1024 + k0 + kc*8, lds + widx*1024);
            gload16(wxt + (size_t)(gc0 + mt*32 + r5)*1024 + k0 + kc*8, lds + 16384 + widx*1024);
        }
        __syncthreads();
        bf16x8 a[4];
        #pragma unroll
        for (int ks = 0; ks < 4; ++ks)
            a[ks] = *(const bf16x8*)(lds + w*4096 + (ks*2 + (lane>>5))*512 + (lane&31)*16);
        #pragma unroll
        for (int nt = 0; nt < 4; ++nt) {
            #pragma unroll
            for (int ks = 0; ks < 4; ++ks) {
                bf16x8 b = *(const bf16x8*)(lds + 16384 + nt*4096 + (ks*2 + (lane>>5))*512 + (lane&31)*16);
                acc[nt] = __builtin_amdgcn_mfma_f32_32x32x16_bf16(a[ks], b, acc[nt], 0, 0, 0);
            }
        }
        __syncthreads();
    }
    const int b_idx = n0 >> 8;
    const int t_base = n0 & 255;
    #pragma unroll
    for (int nt = 0; nt < 4; ++nt) {
        int gc = gc0 + nt*32 + (lane & 31);
        int gate = gc >> 10, col = gc & 1023;
        const float* bp = gate == 0 ? b0 : gate == 1 ? b1 : gate == 2 ? b2 : b3;
        float bias = bp[col];
        #pragma unroll
        for (int r = 0; r < 16; ++r) {
            int row = (r & 3) + 8*(r >> 2) + 4*(lane >> 5);
            int t = t_base + w*32 + row;
            p2[((size_t)t*32 + b_idx)*4096 + gc] = f2bf(acc[nt][r] + bias);
        }
    }
}

// ---------------- persistent BiLSTM recurrence ----------------
#define WPK   0          // 64 KB weight pack (B-frag order, 16x16x32)
#define HFO   65536      // 32 KB h stage, dir F (A-frag order, xor-swizzled)
#define HBO   98304      // 32 KB h stage, dir B
#define REDF  131072     // 4 KB K-split partials F
#define REDB  135168     // 4 KB partials B
#define CSTO  139264     // 1 KB c-state
#define STH_H 140288     // 512 B h bf16 stash [2 dir][16 row][8 col]
#define STH_O 140800     // 1 KB out fp32 stash [2 dir][16 row][8 col]
#define LDS_TOT 141824

extern __shared__ char smem[];

#define WAIT_VM0()  do { asm volatile("s_waitcnt vmcnt(0)" ::: "memory"); \
                         __builtin_amdgcn_sched_barrier(0); } while (0)
#define WAIT_LGKM0() do { asm volatile("s_waitcnt lgkmcnt(0)" ::: "memory"); \
                         __builtin_amdgcn_sched_barrier(0); } while (0)
#define BARRIER()   do { __builtin_amdgcn_s_barrier(); \
                         __builtin_amdgcn_sched_barrier(0); } while (0)

__global__ __launch_bounds__(256, 1) void k_lstm(
    const float* __restrict__ Wf, const float* __restrict__ Wi,
    const float* __restrict__ Wc, const float* __restrict__ Wo,
    const unsigned short* __restrict__ p2,
    unsigned short* __restrict__ hbuf,   // [2 dir][2 slot][32][1024] bf16
    unsigned* __restrict__ fl,           // flags u32 @ 64B stride: [half][128]
    float* __restrict__ out)             // [32][256][2048] fp32
{
    const int wg = blockIdx.x;
    const int bh = wg & 1;               // batch half (own dependency group)
    const int hc0 = (wg >> 1) * 8;       // owned h-cols
    const int tid = threadIdx.x;
    const int lane = tid & 63, w = tid >> 6;
    __shared__ int s_abort;
    if (tid == 0) s_abort = 0;

    const int d2 = tid >> 7, t2 = tid & 127;
    const int eb = t2 >> 3, ehc = t2 & 7;
    const int ebg = bh*16 + eb, ehcg = hc0 + ehc;

    // ---- P(0) prefetch (earliest possible; hides under weight pack) ----
    unsigned short pf_c, pi_c, pc_c, po_c;
    {
        const unsigned short* pp = p2 + ((size_t)(d2 ? 255 : 0)*32 + ebg)*4096 + ehcg;
        pf_c = pp[0]; pi_c = pp[1024]; pc_c = pp[2048]; po_c = pp[3072];
    }

    // ---- pack recurrent weights (h-part rows 0..1023) into LDS frag order ----
    {
        unsigned short* scr = (unsigned short*)(smem + HFO);
        const float* Wp[4] = {Wf, Wi, Wc, Wo};
        for (int blk = 0; blk < 16; ++blk) {
            int r0 = blk * 64;
            {
                int g = tid >> 6, r = tid & 63;
                const float* src = Wp[g] + (size_t)(r0 + r) * 1024 + hc0;
                float4 v0 = *(const float4*)src;
                float4 v1 = *(const float4*)(src + 4);
                unsigned short* d = scr + r*32 + g*8;
                d[0]=f2bf(v0.x); d[1]=f2bf(v0.y); d[2]=f2bf(v0.z); d[3]=f2bf(v0.w);
                d[4]=f2bf(v1.x); d[5]=f2bf(v1.y); d[6]=f2bf(v1.z); d[7]=f2bf(v1.w);
            }
            __syncthreads();
            {
                int ksl = tid >> 7, nt = (tid >> 6) & 1, l = tid & 63;
                int gcl = nt*16 + (l & 15);
                int gp = gcl >> 3, hc = gcl & 7;
                int ks = (r0 >> 5) + ksl;
                unsigned short tmp[8];
                #pragma unroll
                for (int j = 0; j < 8; ++j) {
                    int kloc = ksl*32 + (l >> 4)*8 + j;
                    tmp[j] = scr[kloc*32 + gp*8 + hc];
                }
                char* dst = smem + WPK + (size_t)((nt*32 + ks)*64 + l)*16;
                ushort4 lo, hi;
                lo.x=tmp[0]; lo.y=tmp[1]; lo.z=tmp[2]; lo.w=tmp[3];
                hi.x=tmp[4]; hi.y=tmp[5]; hi.z=tmp[6]; hi.w=tmp[7];
                *(ushort4*)dst = lo; *((ushort4*)dst + 1) = hi;
            }
            __syncthreads();
        }
    }

    // ---- init c=0 (LDS), h[0]=0 (global), publish tag 1 ----
    for (int i = tid; i < 256; i += 256) ((float*)(smem + CSTO))[i] = 0.0f;
    if ((tid & 1) == 0) {
        unsigned* dst = (unsigned*)(hbuf + ((size_t)d2*2 + 0)*32768 + (size_t)ebg*1024 + ehcg);
        __hip_atomic_store(dst, 0u, __ATOMIC_RELAXED, __HIP_MEMORY_SCOPE_AGENT);
    }
    __syncthreads();                              // drains init stores (vmcnt0)
    if (tid == 0)
        __hip_atomic_store(fl + (size_t)bh*2048 + (wg >> 1)*16, 1u,
                           __ATOMIC_RELAXED, __HIP_MEMORY_SCOPE_AGENT);

    for (int s = 0; s < 256; ++s) {
        const int slot = s & 1, nslot = slot ^ 1;
        const unsigned tag = (unsigned)(s + 1);
        const int sn = (s + 1 < 256) ? s + 1 : s;
        const int txn = d2 ? (255 - sn) : sn;
        const unsigned short* ppn = p2 + ((size_t)txn*32 + ebg)*4096 + ehcg;
        unsigned short pf_n = 0, pi_n = 0, pc_n = 0, po_n = 0;

        // W1/W2: issue next-step P prefetch now (overlaps W0's poll; their
        // vmcnt is not waited until far later).
        if (w == 1 || w == 2) {
            pf_n = ppn[0]; pi_n = ppn[1024]; pc_n = ppn[2048]; po_n = ppn[3072];
        }

        // ---- W0: poll own half's 128 flags (2 per lane) ----
        if (w == 0) {
            const unsigned* p0 = fl + (size_t)bh*2048 + lane*16;
            const unsigned* p1 = p0 + 64*16;
            long guard = 0;
            for (;;) {
                unsigned a = __hip_atomic_load(p0, __ATOMIC_RELAXED, __HIP_MEMORY_SCOPE_AGENT);
                unsigned b = __hip_atomic_load(p1, __ATOMIC_RELAXED, __HIP_MEMORY_SCOPE_AGENT);
                if (__all((a >= tag) && (b >= tag))) break;
                if (++guard >= (1L << 21)) { if (lane == 0) s_abort = 1; break; }
                __builtin_amdgcn_s_sleep(1);
            }
            WAIT_LGKM0();                         // s_abort write (if any) visible
        }
        BARRIER();                                // B1: step ready
        if (s_abort) break;

        // ---- staging: W0 -> dir F, W3 -> dir B (32 x 1KB chunks each) ----
        if (w == 0 || w == 3) {
            const unsigned short* hs = hbuf + ((size_t)((w == 3) ? 1 : 0)*2 + slot)*32768;
            char* dstb = smem + ((w == 3) ? HBO : HFO);
            #pragma unroll
            for (int j = 0; j < 32; ++j) {
                int kc = j*4 + (lane >> 4);
                int r16 = (lane & 15) ^ (kc & 7);
                gload16a(hs + (size_t)(bh*16 + r16)*1024 + kc*8, dstb + j*1024);
            }
            WAIT_VM0();                           // own gloads only (clean vmcnt)
        }
        BARRIER();                                // B2: h staged
        // staging waves: issue next-P now that their vmcnt is clean
        if (w == 0 || w == 3) {
            pf_n = ppn[0]; pi_n = ppn[1024]; pc_n = ppn[2048]; po_n = ppn[3072];
        }

        // ---- MFMA: gates = h @ Wh (M=16, N=32, K=1024), K split across wave pairs ----
        {
            const int nt = w & 1, kh = w >> 1;
            f32x4 aF = {0.f,0.f,0.f,0.f}, aB = {0.f,0.f,0.f,0.f};
            #pragma unroll 4
            for (int k8 = 0; k8 < 16; ++k8) {
                int ks = kh*16 + k8;
                int kc = ks*4 + (lane >> 4);
                int ao = kc*256 + (((lane & 15)*16) ^ ((kc & 7) << 4));
                bf16x8 bfr = *(const bf16x8*)(smem + WPK + (size_t)((nt*32 + ks)*64 + lane)*16);
                bf16x8 afF = *(const bf16x8*)(smem + HFO + ao);
                aF = __builtin_amdgcn_mfma_f32_16x16x32_bf16(afF, bfr, aF, 0, 0, 0);
                bf16x8 afB = *(const bf16x8*)(smem + HBO + ao);
                aB = __builtin_amdgcn_mfma_f32_16x16x32_bf16(afB, bfr, aB, 0, 0, 0);
            }
            float* rf = (float*)(smem + REDF) + w*256;
            float* rb = (float*)(smem + REDB) + w*256;
            #pragma unroll
            for (int r = 0; r < 4; ++r) {
                int row = (lane >> 4)*4 + r;
                rf[row*16 + (lane & 15)] = aF[r];
                rb[row*16 + (lane & 15)] = aB[r];
            }
        }
        WAIT_LGKM0();                             // red partials visible
        BARRIER();                                // B3: partials ready

        // ---- elementwise: t<128 does F, t>=128 does B; stash h+out in LDS ----
        {
            const char* red = smem + (d2 ? REDB : REDF);
            float* cst = (float*)(smem + CSTO) + (size_t)(d2*16 + eb)*8 + ehc;
            unsigned short pv[4] = {pf_c, pi_c, pc_c, po_c};
            float pre[4];
            #pragma unroll
            for (int g = 0; g < 4; ++g) {
                int gc = g*8 + ehc;
                int nt = gc >> 4, col = gc & 15;
                float s0 = ((const float*)red)[nt*256 + eb*16 + col];
                float s1 = ((const float*)red)[(2 + nt)*256 + eb*16 + col];
                pre[g] = s0 + s1 + bf2f(pv[g]);
            }
            float fg = sigm(pre[0]), ig = sigm(pre[1]), gg = tanh_(pre[2]), og = sigm(pre[3]);
            float cn = fg * (*cst) + ig * gg;
            *cst = cn;
            float hv = og * tanh_(cn);
            ((unsigned short*)(smem + STH_H))[d2*128 + t2] = f2bf(hv);
            ((float*)(smem + STH_O))[d2*128 + t2] = hv;
        }
        WAIT_LGKM0();                             // stash visible
        BARRIER();                                // B4: stash ready

        // ---- W2: h publish (64 x 8B agent stores) + drain + flag ----
        if (w == 2) {
            int chunk = lane >> 1, half = lane & 1;   // chunk = d2s*16 + ebs
            int d2s = chunk >> 4, ebs = chunk & 15;
            unsigned long long v = *(const unsigned long long*)(smem + STH_H + chunk*16 + half*8);
            unsigned long long* dst = (unsigned long long*)(hbuf
                + ((size_t)d2s*2 + nslot)*32768
                + (size_t)(bh*16 + ebs)*1024 + hc0 + half*4);
            __hip_atomic_store(dst, v, __ATOMIC_RELAXED, __HIP_MEMORY_SCOPE_AGENT);
            WAIT_VM0();                           // h stores (+old P loads) drained
            if (lane == 0)
                __hip_atomic_store(fl + (size_t)bh*2048 + (wg >> 1)*16, (unsigned)(s + 2),
                                   __ATOMIC_RELAXED, __HIP_MEMORY_SCOPE_AGENT);
        }
        // ---- W1: out stores (16B), never waited in-loop ----
        if (w == 1) {
            int chunk = lane >> 1, half = lane & 1;
            int d2s = chunk >> 4, ebs = chunk & 15;
            int txs = d2s ? (255 - s) : s;
            float4 v = *(const float4*)(smem + STH_O + chunk*32 + half*16);
            *(float4*)(out + ((size_t)(bh*16 + ebs)*256 + txs)*2048
                           + (size_t)d2s*1024 + hc0 + half*4) = v;
        }
        // rotate P regs (static, no runtime indexing)
        pf_c = pf_n; pi_c = pi_n; pc_c = pc_n; po_c = po_n;
        // W0 falls through to next poll immediately (overlaps W2's drain+flag)
    }
}

extern "C" void kernel_launch(void* const* d_in, const int* in_sizes, int n_in,
                              void* d_out, int out_size, void* d_ws, size_t ws_size,
                              hipStream_t stream) {
    const float* x  = (const float*)d_in[0];
    const float* Wf = (const float*)d_in[1]; const float* bf_ = (const float*)d_in[2];
    const float* Wi = (const float*)d_in[3]; const float* bi_ = (const float*)d_in[4];
    const float* Wc = (const float*)d_in[5]; const float* bc_ = (const float*)d_in[6];
    const float* Wo = (const float*)d_in[7]; const float* bo_ = (const float*)d_in[8];
    char* ws = (char*)d_ws;
    unsigned short* xb   = (unsigned short*)(ws + XB_OFF);
    unsigned short* wxt  = (unsigned short*)(ws + WXT_OFF);
    unsigned short* p2   = (unsigned short*)(ws + P2_OFF);
    unsigned short* hbuf = (unsigned short*)(ws + HB_OFF);
    unsigned*       fl   = (unsigned*)(ws + FLG_OFF);

    hipMemsetAsync(ws + FLG_OFF, 0, FLG_SZ, stream);
    k_cvt_x<<<8192, 256, 0, stream>>>(x, xb, 32*256*1024);
    k_pack_wxt<<<dim3(16, 64), 256, 0, stream>>>(Wf, Wi, Wc, Wo, wxt);
    k_pgemm<<<dim3(64, 32), 256, 0, stream>>>(xb, wxt, bf_, bi_, bc_, bo_, p2);
    hipFuncSetAttribute((const void*)k_lstm, hipFuncAttributeMaxDynamicSharedMemorySize, LDS_TOT);
    k_lstm<<<256, 256, LDS_TOT, stream>>>(Wf, Wi, Wc, Wo, p2, hbuf, fl, (float*)d_out);
}

// Round 9
// 2386.868 us; speedup vs baseline: 1.0682x; 1.0609x over previous
//
#include <hip/hip_runtime.h>
#include <stdint.h>

// BiLSTM: B=32, T=256, D=1024, H=1024. out (B,T,2H) fp32.
//  k_cvt_x   : x fp32 -> bf16
//  k_pack_wxt: x-part of W{f,i,c,o} -> Wx^T bf16 [4096 gc][1024 k]
//  k_pgemm   : P[t][b][gc] = x@Wx + b (bf16 MFMA 32x32x16), shared by both dirs
//  k_lstm    : persistent 256-WG kernel; weights in LDS; h exchanged per step.
// R9 = R8 with the inline-asm constraint fixed (ext_vector payload, not uint4).
// R8 (base R5): h broadcast made L2-CACHEABLE via per-step ring buffer.
//   sc1 staging (16 MB/step LLC-coherent burst) was the floor: each of 256
//   consumers re-fetched 64 KB from LLC. Now: publish h(s+1) into virgin ring
//   slot s+1 (sc1 stores -> LLC), consumers read with PLAIN CACHED loads ->
//   each XCD fetches each line once (MSHR merge), L2 serves the other 31 WGs.
//   1 MB/step LLC traffic instead of 16. Staleness: slots never reused within
//   a launch; dispatch-boundary acquire invalidates L2 across launches
//   (empirically confirmed since R1: k_pgemm reads k_cvt_x output cached).
//   Ring (32 MB) overlays dead xb/wxt; p2 relocated. Publish: 32x16B stores.

typedef __attribute__((ext_vector_type(8))) short bf16x8;
typedef __attribute__((ext_vector_type(4))) float f32x4;
typedef __attribute__((ext_vector_type(16))) float f32x16;
typedef __attribute__((ext_vector_type(4))) unsigned int u32x4;

// ---- workspace layout (bytes) ----
// [0, 32M)    : h ring [256 slots][2 dir][32 rows][1024 cols] bf16 (k_lstm)
//               xb (16 MB @0) and wxt (8 MB @16M) live here during prep only.
static const size_t XB_OFF  = 0;                 // x bf16: 16 MB (dead in k_lstm)
static const size_t WXT_OFF = 16777216;          // Wx^T bf16: 8 MB (dead in k_lstm)
static const size_t P2_OFF  = 33554432;          // P bf16 [256][32][4096] = 64 MB
static const size_t FLG_OFF = 100663296;         // flags u32 @64B stride: [2 half][128]
static const size_t FLG_SZ  = 16384;

__device__ __forceinline__ unsigned short f2bf(float f) {
    union { float f; unsigned u; } v; v.f = f;
    unsigned r = v.u + 0x7FFFu + ((v.u >> 16) & 1u);
    return (unsigned short)(r >> 16);
}
__device__ __forceinline__ float bf2f(unsigned short h) {
    union { unsigned u; float f; } v; v.u = ((unsigned)h) << 16; return v.f;
}
__device__ __forceinline__ float sigm(float x) {
    return 1.0f / (1.0f + exp2f(x * -1.4426950408889634f));
}
__device__ __forceinline__ float tanh_(float x) {
    return 1.0f - 2.0f / (1.0f + exp2f(x * 2.8853900817779268f));
}
__device__ __forceinline__ void gload16(const void* g, void* l) {
    __builtin_amdgcn_global_load_lds(
        (const __attribute__((address_space(1))) unsigned int*)g,
        (__attribute__((address_space(3))) unsigned int*)l, 16, 0, 0);
}
// 16B store direct to LLC (sc1): publish path for cross-WG h.
// Payload must be an ext_vector (maps to a VGPR quad for the "v" constraint).
__device__ __forceinline__ void gstore16_sc1(void* g, u32x4 v) {
    asm volatile("global_store_dwordx4 %0, %1, off sc1" : : "v"(g), "v"(v) : "memory");
}

// ---------------- x -> bf16 ----------------
__global__ void k_cvt_x(const float* __restrict__ x, unsigned short* __restrict__ xb, int n) {
    int i = (blockIdx.x * blockDim.x + threadIdx.x) * 4;
    if (i < n) {
        float4 v = *(const float4*)(x + i);
        ushort4 o; o.x = f2bf(v.x); o.y = f2bf(v.y); o.z = f2bf(v.z); o.w = f2bf(v.w);
        *(ushort4*)(xb + i) = o;
    }
}

// ---------------- Wx^T pack ----------------
__global__ __launch_bounds__(256) void k_pack_wxt(
        const float* __restrict__ Wf, const float* __restrict__ Wi,
        const float* __restrict__ Wc, const float* __restrict__ Wo,
        unsigned short* __restrict__ wxt) {
    __shared__ unsigned short tile[64][66];
    const int k0 = blockIdx.x * 64;
    const int gate = blockIdx.y >> 4;
    const int c0 = (blockIdx.y & 15) * 64;
    const float* W = gate == 0 ? Wf : gate == 1 ? Wi : gate == 2 ? Wc : Wo;
    const int t = threadIdx.x;
    #pragma unroll
    for (int i = 0; i < 4; ++i) {
        int id = t + 256 * i;
        int r = id >> 4, fq = id & 15;
        const float* src = W + (size_t)(1024 + k0 + r) * 1024 + c0 + fq * 4;
        float4 v = *(const float4*)src;
        tile[r][fq*4+0] = f2bf(v.x); tile[r][fq*4+1] = f2bf(v.y);
        tile[r][fq*4+2] = f2bf(v.z); tile[r][fq*4+3] = f2bf(v.w);
    }
    __syncthreads();
    #pragma unroll
    for (int i = 0; i < 2; ++i) {
        int id = t + 256 * i;
        int c = id >> 3, kq = id & 7;
        ushort4 a, b;
        a.x = tile[kq*8+0][c]; a.y = tile[kq*8+1][c]; a.z = tile[kq*8+2][c]; a.w = tile[kq*8+3][c];
        b.x = tile[kq*8+4][c]; b.y = tile[kq*8+5][c]; b.z = tile[kq*8+6][c]; b.w = tile[kq*8+7][c];
        unsigned short* o = wxt + (size_t)(gate*1024 + c0 + c) * 1024 + k0 + kq*8;
        *(ushort4*)o = a;
        *((ushort4*)o + 1) = b;
    }
}

// ---------------- P GEMM ----------------
__global__ __launch_bounds__(256) void k_pgemm(
        const unsigned short* __restrict__ xb, const unsigned short* __restrict__ wxt,
        const float* __restrict__ b0, const float* __restrict__ b1,
        const float* __restrict__ b2, const float* __restrict__ b3,
        unsigned short* __restrict__ p2) {
    __shared__ char lds[32768];
    const int n0 = blockIdx.x * 128;
    const int gc0 = blockIdx.y * 128;
    const int tid = threadIdx.x;
    const int lane = tid & 63, w = tid >> 6;
    f32x16 acc[4];
    #pragma unroll
    for (int i = 0; i < 4; ++i)
        #pragma unroll
        for (int j = 0; j < 16; ++j) acc[i][j] = 0.0f;

    for (int kt = 0; kt < 16; ++kt) {
        const int k0 = kt * 64;
        #pragma unroll
        for (int i = 0; i < 4; ++i) {
            int widx = w*4 + i;
            int n = widx*64 + lane;
            int mt = n >> 8, kc = (n >> 5) & 7, r5 = n & 31;
            gload16(xb  + (size_t)(n0  + mt*32 + r5)*1024 + k0 + kc*8, lds + widx*1024);
            gload16(wxt + (size_t)(gc0 + mt*32 + r5)*1024 + k0 + kc*8, lds + 16384 + widx*1024);
        }
        __syncthreads();
        bf16x8 a[4];
        #pragma unroll
        for (int ks = 0; ks < 4; ++ks)
            a[ks] = *(const bf16x8*)(lds + w*4096 + (ks*2 + (lane>>5))*512 + (lane&31)*16);
        #pragma unroll
        for (int nt = 0; nt < 4; ++nt) {
            #pragma unroll
            for (int ks = 0; ks < 4; ++ks) {
                bf16x8 b = *(const bf16x8*)(lds + 16384 + nt*4096 + (ks*2 + (lane>>5))*512 + (lane&31)*16);
                acc[nt] = __builtin_amdgcn_mfma_f32_32x32x16_bf16(a[ks], b, acc[nt], 0, 0, 0);
            }
        }
        __syncthreads();
    }
    const int b_idx = n0 >> 8;
    const int t_base = n0 & 255;
    #pragma unroll
    for (int nt = 0; nt < 4; ++nt) {
        int gc = gc0 + nt*32 + (lane & 31);
        int gate = gc >> 10, col = gc & 1023;
        const float* bp = gate == 0 ? b0 : gate == 1 ? b1 : gate == 2 ? b2 : b3;
        float bias = bp[col];
        #pragma unroll
        for (int r = 0; r < 16; ++r) {
            int row = (r & 3) + 8*(r >> 2) + 4*(lane >> 5);
            int t = t_base + w*32 + row;
            p2[((size_t)t*32 + b_idx)*4096 + gc] = f2bf(acc[nt][r] + bias);
        }
    }
}

// ---------------- persistent BiLSTM recurrence ----------------
#define WPK   0          // 64 KB weight pack (B-frag order, 16x16x32)
#define HFO   65536      // 32 KB h stage, dir F (A-frag order, xor-swizzled)
#define HBO   98304      // 32 KB h stage, dir B
#define REDF  131072     // 4 KB K-split partials F
#define REDB  135168     // 4 KB partials B
#define CSTO  139264     // 1 KB c-state
#define STH_H 140288     // 512 B h bf16 stash [2 dir][16 row][8 col]
#define STH_O 140800     // 1 KB out fp32 stash [2 dir][16 row][8 col]
#define LDS_TOT 141824

extern __shared__ char smem[];

__global__ __launch_bounds__(256, 1) void k_lstm(
    const float* __restrict__ Wf, const float* __restrict__ Wi,
    const float* __restrict__ Wc, const float* __restrict__ Wo,
    const unsigned short* __restrict__ p2,
    unsigned short* __restrict__ hring,  // [256 slot][2 dir][32][1024] bf16
    unsigned* __restrict__ fl,           // flags u32 @ 64B stride: [half][128]
    float* __restrict__ out)             // [32][256][2048] fp32
{
    const int wg = blockIdx.x;
    const int bh = wg & 1;               // batch half (own dependency group)
    const int hc0 = (wg >> 1) * 8;       // owned h-cols
    const int tid = threadIdx.x;
    const int lane = tid & 63, w = tid >> 6;
    __shared__ int s_abort;
    if (tid == 0) s_abort = 0;

    // ---- pack recurrent weights (h-part rows 0..1023) into LDS frag order ----
    {
        unsigned short* scr = (unsigned short*)(smem + HFO);
        const float* Wp[4] = {Wf, Wi, Wc, Wo};
        for (int blk = 0; blk < 16; ++blk) {
            int r0 = blk * 64;
            {
                int g = tid >> 6, r = tid & 63;
                const float* src = Wp[g] + (size_t)(r0 + r) * 1024 + hc0;
                float4 v0 = *(const float4*)src;
                float4 v1 = *(const float4*)(src + 4);
                unsigned short* d = scr + r*32 + g*8;
                d[0]=f2bf(v0.x); d[1]=f2bf(v0.y); d[2]=f2bf(v0.z); d[3]=f2bf(v0.w);
                d[4]=f2bf(v1.x); d[5]=f2bf(v1.y); d[6]=f2bf(v1.z); d[7]=f2bf(v1.w);
            }
            __syncthreads();
            {
                int ksl = tid >> 7, nt = (tid >> 6) & 1, l = tid & 63;
                int gcl = nt*16 + (l & 15);
                int gp = gcl >> 3, hc = gcl & 7;
                int ks = (r0 >> 5) + ksl;
                unsigned short tmp[8];
                #pragma unroll
                for (int j = 0; j < 8; ++j) {
                    int kloc = ksl*32 + (l >> 4)*8 + j;
                    tmp[j] = scr[kloc*32 + gp*8 + hc];
                }
                char* dst = smem + WPK + (size_t)((nt*32 + ks)*64 + l)*16;
                ushort4 lo, hi;
                lo.x=tmp[0]; lo.y=tmp[1]; lo.z=tmp[2]; lo.w=tmp[3];
                hi.x=tmp[4]; hi.y=tmp[5]; hi.z=tmp[6]; hi.w=tmp[7];
                *(ushort4*)dst = lo; *((ushort4*)dst + 1) = hi;
            }
            __syncthreads();
        }
    }

    // ---- init c=0 (LDS), h(0)=0 into ring slot 0, publish tag 1 ----
    for (int i = tid; i < 256; i += 256) ((float*)(smem + CSTO))[i] = 0.0f;
    const int d2 = tid >> 7, t2 = tid & 127;
    const int eb = t2 >> 3, ehc = t2 & 7;
    const int ebg = bh*16 + eb, ehcg = hc0 + ehc;
    if ((tid & 1) == 0) {
        unsigned* dst = (unsigned*)(hring + (size_t)d2*32768 + (size_t)ebg*1024 + ehcg);
        __hip_atomic_store(dst, 0u, __ATOMIC_RELAXED, __HIP_MEMORY_SCOPE_AGENT);
    }
    __syncthreads();                              // drains init stores (vmcnt0)
    if (tid == 0)
        __hip_atomic_store(fl + (size_t)bh*2048 + (wg >> 1)*16, 1u,
                           __ATOMIC_RELAXED, __HIP_MEMORY_SCOPE_AGENT);

    for (int s = 0; s < 256; ++s) {
        const int tx = d2 ? (255 - s) : s;
        // P prefetch (cached; no h dependency; hidden under spin+staging)
        const unsigned short* pp = p2 + ((size_t)tx*32 + ebg)*4096 + ehcg;
        unsigned short pf = pp[0], pi = pp[1024], pc = pp[2048], po = pp[3072];

        // ---- wait: own half's 128 flags >= s+1 (waves 0+1, one lane/flag) ----
        if (w < 2) {
            const unsigned* pw = fl + (size_t)bh*2048 + (w*64 + lane)*16;
            const unsigned tag = (unsigned)(s + 1);
            long guard = 0;
            for (;;) {
                unsigned v = __hip_atomic_load(pw, __ATOMIC_RELAXED, __HIP_MEMORY_SCOPE_AGENT);
                if (__all(v >= tag)) break;
                if (++guard >= (1L << 21)) { if (lane == 0) s_abort = 1; break; }
                __builtin_amdgcn_s_sleep(1);
            }
        }
        __syncthreads();
        if (s_abort) break;

        // ---- stage h (both dirs) from ring slot s: PLAIN CACHED gload16 ----
        // (L2 serves 31 of 32 WGs per XCD; slot is virgin -> no staleness)
        {
            const unsigned short* hsF = hring + (size_t)s*65536;
            const unsigned short* hsB = hsF + 32768;
            #pragma unroll
            for (int j = 0; j < 8; ++j) {
                int c = w*8 + j;                  // chunks 0..31
                int kc = c*4 + (lane >> 4);
                int r16 = (lane & 15) ^ (kc & 7);
                size_t off = (size_t)(bh*16 + r16)*1024 + kc*8;
                gload16(hsF + off, smem + HFO + c*1024);
                gload16(hsB + off, smem + HBO + c*1024);
            }
        }
        __syncthreads();                          // drains vmcnt (staging + P)

        // ---- MFMA: gates = h @ Wh (M=16, N=32, K=1024), K split across wave pairs ----
        {
            const int nt = w & 1, kh = w >> 1;
            f32x4 aF = {0.f,0.f,0.f,0.f}, aB = {0.f,0.f,0.f,0.f};
            #pragma unroll 4
            for (int k8 = 0; k8 < 16; ++k8) {
                int ks = kh*16 + k8;
                int kc = ks*4 + (lane >> 4);
                int ao = kc*256 + (((lane & 15)*16) ^ ((kc & 7) << 4));
                bf16x8 bfr = *(const bf16x8*)(smem + WPK + (size_t)((nt*32 + ks)*64 + lane)*16);
                bf16x8 afF = *(const bf16x8*)(smem + HFO + ao);
                aF = __builtin_amdgcn_mfma_f32_16x16x32_bf16(afF, bfr, aF, 0, 0, 0);
                bf16x8 afB = *(const bf16x8*)(smem + HBO + ao);
                aB = __builtin_amdgcn_mfma_f32_16x16x32_bf16(afB, bfr, aB, 0, 0, 0);
            }
            float* rf = (float*)(smem + REDF) + w*256;
            float* rb = (float*)(smem + REDB) + w*256;
            #pragma unroll
            for (int r = 0; r < 4; ++r) {
                int row = (lane >> 4)*4 + r;
                rf[row*16 + (lane & 15)] = aF[r];
                rb[row*16 + (lane & 15)] = aB[r];
            }
        }
        __syncthreads();

        // ---- elementwise: t<128 does F, t>=128 does B; stash h+out in LDS ----
        {
            const char* red = smem + (d2 ? REDB : REDF);
            float* cst = (float*)(smem + CSTO) + (size_t)(d2*16 + eb)*8 + ehc;
            unsigned short pv[4] = {pf, pi, pc, po};
            float pre[4];
            #pragma unroll
            for (int g = 0; g < 4; ++g) {
                int gc = g*8 + ehc;
                int nt = gc >> 4, col = gc & 15;
                float s0 = ((const float*)red)[nt*256 + eb*16 + col];
                float s1 = ((const float*)red)[(2 + nt)*256 + eb*16 + col];
                pre[g] = s0 + s1 + bf2f(pv[g]);
            }
            float fg = sigm(pre[0]), ig = sigm(pre[1]), gg = tanh_(pre[2]), og = sigm(pre[3]);
            float cn = fg * (*cst) + ig * gg;
            *cst = cn;
            float hv = og * tanh_(cn);
            ((unsigned short*)(smem + STH_H))[d2*128 + t2] = f2bf(hv);
            ((float*)(smem + STH_O))[d2*128 + t2] = hv;
        }
        __syncthreads();

        // ---- h publish into virgin ring slot s+1: 32 x 16B sc1 stores ----
        if (s < 255) {
            if (tid < 32) {
                int d2s = tid >> 4, ebs = tid & 15;
                u32x4 v = *(const u32x4*)(smem + STH_H + (d2s*16 + ebs)*16);
                gstore16_sc1(hring + (size_t)(s + 1)*65536 + (size_t)d2s*32768
                                   + (size_t)(bh*16 + ebs)*1024 + hc0, v);
            }
            __syncthreads();                      // drains h stores (vmcnt0)
            if (tid == 0)
                __hip_atomic_store(fl + (size_t)bh*2048 + (wg >> 1)*16, (unsigned)(s + 2),
                                   __ATOMIC_RELAXED, __HIP_MEMORY_SCOPE_AGENT);
        }

        // ---- out stores (post-publish, off critical path): 16B chunks ----
        if (tid >= 64 && tid < 128) {
            int i = tid - 64;
            int chunk = i >> 1, half = i & 1;       // chunk = d2s*16 + ebs
            int d2s = chunk >> 4, ebs = chunk & 15;
            int txs = d2s ? (255 - s) : s;
            float4 v = *(const float4*)(smem + STH_O + chunk*32 + half*16);
            *(float4*)(out + ((size_t)(bh*16 + ebs)*256 + txs)*2048
                           + (size_t)d2s*1024 + hc0 + half*4) = v;
        }
    }
}

extern "C" void kernel_launch(void* const* d_in, const int* in_sizes, int n_in,
                              void* d_out, int out_size, void* d_ws, size_t ws_size,
                              hipStream_t stream) {
    const float* x  = (const float*)d_in[0];
    const float* Wf = (const float*)d_in[1]; const float* bf_ = (const float*)d_in[2];
    const float* Wi = (const float*)d_in[3]; const float* bi_ = (const float*)d_in[4];
    const float* Wc = (const float*)d_in[5]; const float* bc_ = (const float*)d_in[6];
    const float* Wo = (const float*)d_in[7]; const float* bo_ = (const float*)d_in[8];
    char* ws = (char*)d_ws;
    unsigned short* xb    = (unsigned short*)(ws + XB_OFF);
    unsigned short* wxt   = (unsigned short*)(ws + WXT_OFF);
    unsigned short* p2    = (unsigned short*)(ws + P2_OFF);
    unsigned short* hring = (unsigned short*)(ws + XB_OFF);   // overlays dead xb/wxt
    unsigned*       fl    = (unsigned*)(ws + FLG_OFF);

    hipMemsetAsync(ws + FLG_OFF, 0, FLG_SZ, stream);
    k_cvt_x<<<8192, 256, 0, stream>>>(x, xb, 32*256*1024);
    k_pack_wxt<<<dim3(16, 64), 256, 0, stream>>>(Wf, Wi, Wc, Wo, wxt);
    k_pgemm<<<dim3(64, 32), 256, 0, stream>>>(xb, wxt, bf_, bi_, bc_, bo_, p2);
    hipFuncSetAttribute((const void*)k_lstm, hipFuncAttributeMaxDynamicSharedMemorySize, LDS_TOT);
    k_lstm<<<256, 256, LDS_TOT, stream>>>(Wf, Wi, Wc, Wo, p2, hring, fl, (float*)d_out);
}